// Round 12
// baseline (387.961 us; speedup 1.0000x reference)
//
#include <hip/hip_runtime.h>
#include <cstdint>
#include <cstddef>

// DinoDecoderBlock on MI355X (gfx950).
// B=4 NQ=NK=1024 C=768 H=12 DH=64, scale=1/8, eps=1e-5.
// R12: bias_k standalone + fully linearized DRAM pattern:
//      reads staged per-wave (contiguous 4KB sim rows -> LDS), writes transposed
//      to [b][q][h][k] (24KB contiguous per block). fattn bias indexing updated.
//      (R10/R11: bias BW pinned at 2.2 TB/s under occupancy/ILP changes ->
//       12x 4MB-strided gather + 2MB-strided scatter = DRAM row thrash.)

typedef __bf16 bf16;
typedef __attribute__((ext_vector_type(8))) __bf16 bf16x8;
typedef __attribute__((ext_vector_type(4))) __bf16 bf16x4;
typedef __attribute__((ext_vector_type(4))) float f32x4;

typedef __attribute__((address_space(1))) void gvoid;
typedef __attribute__((address_space(3))) void lvoid;

#define DEVI static __device__ __forceinline__

DEVI void gload16(const void* g, void* l) {
  __builtin_amdgcn_global_load_lds((gvoid*)(uintptr_t)g, (lvoid*)(uintptr_t)l, 16, 0, 0);
}

DEVI f32x4 mfma_bf16(bf16x8 a, bf16x8 b, f32x4 c) {
  return __builtin_amdgcn_mfma_f32_16x16x32_bf16(a, b, c, 0, 0, 0);
}

// ================= device bodies =================

// ---- GEMM tile body ----
template<int BM, int BN, bool BIAS, bool GELU, bool RES, bool OBF, bool VT>
DEVI void gemm_dev(bf16* As, bf16* Bs, int by, int bx,
                   const bf16* __restrict__ A, const bf16* __restrict__ Bt,
                   const float* __restrict__ bias, const float* __restrict__ res,
                   bf16* __restrict__ Cb, float* __restrict__ Cf,
                   bf16* __restrict__ vtOut, int vtBase, int N, int K)
{
  constexpr int WM = BM / 2, WN = BN / 2;
  constexpr int FM = WM / 16, FN = WN / 16;
  const int tid = threadIdx.x;
  const int lane = tid & 63;
  const int wv = tid >> 6;
  const int wr = wv >> 1, wc = wv & 1;
  const int l15 = lane & 15, lg = lane >> 4;
  const int bm = by * BM, bn = bx * BN;

  f32x4 acc[FM][FN];
  const f32x4 z = {0.f, 0.f, 0.f, 0.f};
  #pragma unroll
  for (int i = 0; i < FM; ++i)
    #pragma unroll
    for (int jj = 0; jj < FN; ++jj) acc[i][jj] = z;

  for (int k0 = 0; k0 < K; k0 += 64) {
    __syncthreads();
    #pragma unroll
    for (int c = tid; c < BM * 8; c += 256) {
      const int row = c >> 3, colb = (c & 7) << 4;
      gload16((const char*)A + ((size_t)(bm + row) * K + k0) * 2 + colb,
              (char*)As + (size_t)c * 16);
    }
    #pragma unroll
    for (int c = tid; c < BN * 8; c += 256) {
      const int row = c >> 3, colb = (c & 7) << 4;
      gload16((const char*)Bt + ((size_t)(bn + row) * K + k0) * 2 + colb,
              (char*)Bs + (size_t)c * 16);
    }
    __syncthreads();
    #pragma unroll
    for (int kk = 0; kk < 64; kk += 32) {
      bf16x8 af[FM], bfr[FN];
      #pragma unroll
      for (int mi = 0; mi < FM; ++mi)
        af[mi] = *(const bf16x8*)(As + (size_t)(wr * WM + mi * 16 + l15) * 64 + kk + lg * 8);
      #pragma unroll
      for (int ni = 0; ni < FN; ++ni)
        bfr[ni] = *(const bf16x8*)(Bs + (size_t)(wc * WN + ni * 16 + l15) * 64 + kk + lg * 8);
      #pragma unroll
      for (int mi = 0; mi < FM; ++mi)
        #pragma unroll
        for (int ni = 0; ni < FN; ++ni)
          acc[mi][ni] = mfma_bf16(af[mi], bfr[ni], acc[mi][ni]);
    }
  }

  #pragma unroll
  for (int mi = 0; mi < FM; ++mi) {
    const int row0 = bm + wr * WM + mi * 16 + lg * 4;
    #pragma unroll
    for (int ni = 0; ni < FN; ++ni) {
      const int col = bn + wc * WN + ni * 16 + l15;
      if constexpr (VT) {
        if (col >= vtBase) {   // V channel: store transposed, 4 consecutive n
          const int hd = col - vtBase;            // h*64+d
          const int bb = row0 >> 10, n0 = row0 & 1023;
          bf16x4 ov;
          #pragma unroll
          for (int r = 0; r < 4; ++r) ov[r] = (bf16)acc[mi][ni][r];
          *(bf16x4*)(vtOut + ((size_t)(bb * 768 + hd)) * 1024 + n0) = ov;
          continue;
        }
      }
      #pragma unroll
      for (int r = 0; r < 4; ++r) {
        float v = acc[mi][ni][r];
        if constexpr (BIAS) v += bias[col];
        if constexpr (GELU) v = 0.5f * v * (1.0f + erff(v * 0.70710678118654752f));
        if constexpr (RES)  v += res[(size_t)(row0 + r) * N + col];
        if constexpr (OBF)  Cb[(size_t)(row0 + r) * N + col] = (bf16)v;
        else                Cf[(size_t)(row0 + r) * N + col] = v;
      }
    }
  }
}

// ---- wave-parallel LayerNorm: one wave = one row of 768, no barriers ----
DEVI void lnw_dev(int row,
                  const float* __restrict__ xin, const float* __restrict__ g,
                  const float* __restrict__ be, bf16* __restrict__ out)
{
  const int lane = threadIdx.x & 63;
  const f32x4* xr = (const f32x4*)(xin + (size_t)row * 768);
  f32x4 v[3];
  #pragma unroll
  for (int j = 0; j < 3; ++j) v[j] = xr[lane + 64 * j];
  float s = 0.f;
  #pragma unroll
  for (int j = 0; j < 3; ++j) s += v[j][0] + v[j][1] + v[j][2] + v[j][3];
  #pragma unroll
  for (int o = 32; o; o >>= 1) s += __shfl_xor(s, o);
  const float mean = s * (1.0f / 768.0f);
  float q = 0.f;
  #pragma unroll
  for (int j = 0; j < 3; ++j)
    #pragma unroll
    for (int e = 0; e < 4; ++e) { const float d = v[j][e] - mean; q += d * d; }
  #pragma unroll
  for (int o = 32; o; o >>= 1) q += __shfl_xor(q, o);
  const float inv = rsqrtf(q * (1.0f / 768.0f) + 1e-5f);
  #pragma unroll
  for (int j = 0; j < 3; ++j) {
    const int c = lane + 64 * j;
    const f32x4 gv = ((const f32x4*)g)[c];
    const f32x4 bv = ((const f32x4*)be)[c];
    bf16x4 o4;
    #pragma unroll
    for (int e = 0; e < 4; ++e)
      o4[e] = (bf16)((v[j][e] - mean) * inv * gv[e] + bv[e]);
    *((bf16x4*)out + (size_t)row * 192 + c) = o4;
  }
}

// ================= kernels =================

struct CvtArgs {
  const float* src[8];
  bf16* dst[8];
  int end[8];
};

// D1 (streaming): cvt [0,2304) 4 chunks/thread + LN [2304,4352) wave-parallel
__global__ __launch_bounds__(256)
void prep_k(CvtArgs a,
            const float* __restrict__ x, const float* __restrict__ g1,
            const float* __restrict__ b1, bf16* __restrict__ xn,
            const float* __restrict__ y, const float* __restrict__ gy,
            const float* __restrict__ by_, bf16* __restrict__ yln)
{
  const int f = blockIdx.x;
  const int t = threadIdx.x;
  if (f < 2304) {
    #pragma unroll
    for (int j = 0; j < 4; ++j) {
      const int i = f * 1024 + j * 256 + t;
      int s = 0;
      #pragma unroll
      for (int k = 0; k < 7; ++k) s += (i >= a.end[k]) ? 1 : 0;
      const int base = s ? a.end[s - 1] : 0;
      const int off = i - base;
      const f32x4 v = *((const f32x4*)a.src[s] + off);
      bf16x4 o;
      o[0] = (bf16)v[0]; o[1] = (bf16)v[1]; o[2] = (bf16)v[2]; o[3] = (bf16)v[3];
      *(bf16x4*)(a.dst[s] + (size_t)off * 4) = o;
    }
  } else {
    const int row = (f - 2304) * 4 + (t >> 6);
    if (row < 4096) lnw_dev(row, x, g1, b1, xn);
    else            lnw_dev(row - 4096, y, gy, by_, yln);
  }
}

// D2 (streaming, linearized): one block per (b,q).
// Reads: wave w stages sim rows h in {w,w+4,w+8} (4KB contiguous each) into LDS.
// Writes: bias[b][q][h][k] -> one 24KB contiguous chunk per block.
__global__ __launch_bounds__(256)
void bias_k(const float* __restrict__ sim,
            const unsigned char* __restrict__ mask,
            bf16* __restrict__ biasOut)
{
  __shared__ float S[12 * 1032];      // padded rows, 49.5 KB
  __shared__ int red[4];
  const int blk = blockIdx.x;         // 4096 = b*1024 + q
  const int b = blk >> 10, q = blk & 1023;
  const int t = threadIdx.x, lane = t & 63, w = t >> 6;

  // mask dtype detect (3KB window; int32 0/1 data has zero bytes at idx%4!=0)
  int ds = mask[t * 4 + 1] + mask[t * 4 + 2] + mask[t * 4 + 3];
  #pragma unroll
  for (int o = 32; o; o >>= 1) ds += __shfl_xor(ds, o);
  if (lane == 0) red[w] = ds;

  // stage 12 sim rows (contiguous 4KB each)
  const float* sb = sim + (size_t)b * 12 * 1048576;
  #pragma unroll
  for (int i = 0; i < 3; ++i) {
    const int h = w + i * 4;
    const f32x4* src = (const f32x4*)(sb + ((size_t)h * 1024 + q) * 1024);
    #pragma unroll
    for (int jj = 0; jj < 4; ++jj) {
      const int c = lane + 64 * jj;
      *(f32x4*)(&S[h * 1032 + c * 4]) = src[c];
    }
  }
  __syncthreads();
  const int msh = ((red[0] + red[1] + red[2] + red[3]) == 0) ? 2 : 0;

  const int k4 = t * 4;
  float mb[4];
  if (msh == 0) {
    const uchar4 mv = *(const uchar4*)(mask + (size_t)q * 1024 + k4);
    mb[0] = mv.x ? 0.f : -1e30f; mb[1] = mv.y ? 0.f : -1e30f;
    mb[2] = mv.z ? 0.f : -1e30f; mb[3] = mv.w ? 0.f : -1e30f;
  } else {
    const int4 mv = *(const int4*)((const int*)mask + (size_t)q * 1024 + k4);
    mb[0] = mv.x ? 0.f : -1e30f; mb[1] = mv.y ? 0.f : -1e30f;
    mb[2] = mv.z ? 0.f : -1e30f; mb[3] = mv.w ? 0.f : -1e30f;
  }

  f32x4 acc = {0.f, 0.f, 0.f, 0.f};
  #pragma unroll
  for (int h = 0; h < 12; ++h) acc += *(const f32x4*)(&S[h * 1032 + k4]);
  const f32x4 mean = acc * (1.0f / 12.0f);

  bf16* ob = biasOut + (size_t)(b * 1024 + q) * 12 * 1024;
  #pragma unroll
  for (int h = 0; h < 12; ++h) {
    const f32x4 sv = *(const f32x4*)(&S[h * 1032 + k4]);
    bf16x4 o;
    #pragma unroll
    for (int j = 0; j < 4; ++j)
      o[j] = (bf16)(sv[j] - mean[j] + mb[j]);
    *(bf16x4*)(ob + h * 1024 + k4) = o;
  }
}

// D5: aproj (384) + pkv (384) co-dispatch (both compute-bound GEMMs)
__global__ __launch_bounds__(256)
void apkv_k(const bf16* __restrict__ sa, const bf16* __restrict__ w_ap,
            const float* __restrict__ apb, const float* __restrict__ x,
            float* __restrict__ x1,
            const bf16* __restrict__ yln, const bf16* __restrict__ w_pkv,
            bf16* __restrict__ ckv, bf16* __restrict__ cvtT)
{
  __shared__ bf16 As[128 * 64];
  __shared__ bf16 Bs[128 * 64];
  const int f = blockIdx.x;
  if (f < 384) {
    const int xcd = f & 7, j = f >> 3;
    const int by = xcd + 8 * (j % 8);
    const int bx = j / 8;
    gemm_dev<64,128,true,false,true,false,false>(As, Bs, by, bx,
        sa, w_ap, apb, x, nullptr, x1, nullptr, 0, 768, 768);
  } else {
    const int g = f - 384;
    const int xcd = g & 7, j = g >> 3;
    const int by = xcd + 8 * (j % 4);
    const int bx = j / 4;
    gemm_dev<128,128,false,false,false,true,true>(As, Bs, by, bx,
        yln, w_pkv, nullptr, nullptr, ckv, nullptr, cvtT, 768, 1536, 768);
  }
}

// D12: fc2 (384) + y-copy (512, grid-stride) co-dispatch
__global__ __launch_bounds__(256)
void fc2copy_k(const bf16* __restrict__ hbuf, const bf16* __restrict__ w_f2,
               const float* __restrict__ f2b, const float* __restrict__ x2,
               float* __restrict__ outp,
               const float* __restrict__ y, float* __restrict__ ycopy)
{
  __shared__ bf16 As[128 * 64];
  __shared__ bf16 Bs[128 * 64];
  const int f = blockIdx.x;
  if (f < 384) {
    const int xcd = f & 7, j = f >> 3;
    const int by = xcd + 8 * (j % 8);
    const int bx = j / 8;
    gemm_dev<64,128,true,false,true,false,false>(As, Bs, by, bx,
        hbuf, w_f2, f2b, x2, nullptr, outp, nullptr, 0, 768, 3072);
  } else {
    for (int i = (f - 384) * 256 + threadIdx.x; i < 786432; i += 512 * 256)
      ((f32x4*)ycopy)[i] = ((const f32x4*)y)[i];
  }
}

// standalone GEMM wrapper (qkv / pq / cproj / fc1)
template<int BM, int BN, bool BIAS, bool GELU, bool RES, bool OBF, bool VT>
__global__ __launch_bounds__(256)
void gemm_bt(const bf16* __restrict__ A, const bf16* __restrict__ Bt,
             const float* __restrict__ bias, const float* __restrict__ res,
             bf16* __restrict__ Cb, float* __restrict__ Cf,
             bf16* __restrict__ vtOut, int vtBase,
             int nyPerXcd, int N, int K)
{
  __shared__ bf16 As[BM * 64];
  __shared__ bf16 Bs[BN * 64];
  const int f = blockIdx.x;
  const int xcd = f & 7, j = f >> 3;
  const int by = xcd + 8 * (j % nyPerXcd);
  const int bx = j / nyPerXcd;
  gemm_dev<BM,BN,BIAS,GELU,RES,OBF,VT>(As, Bs, by, bx,
      A, Bt, bias, res, Cb, Cf, vtOut, vtBase, N, K);
}

// standalone LayerNorm (ln2 / ln3): 4 rows/block, wave-parallel
__global__ __launch_bounds__(256)
void ln_k(const float* __restrict__ xin, const float* __restrict__ g,
          const float* __restrict__ be, bf16* __restrict__ out)
{
  lnw_dev(blockIdx.x * 4 + (threadIdx.x >> 6), xin, g, be, out);
}

// ---------------- flash attention: 64 q-rows/block, 4 waves, online softmax ----
// CROSS: bias layout [b][q][h][k] (bf16).
template<int CROSS>
__global__ __launch_bounds__(256, 3)
void fattn_k(const bf16* __restrict__ Qp, int ldq,
             const bf16* __restrict__ Kp, int ldk,
             const bf16* __restrict__ Vt,
             const bf16* __restrict__ bias,
             bf16* __restrict__ Out)
{
  __shared__ bf16 Kl[2][64 * 64];     // 16 KB, [krow][c] swizzled
  __shared__ bf16 Vl[2][64 * 64];     // 16 KB, [d][k]   swizzled
  __shared__ bf16 Pl[4][16 * 72];     // per-wave P tile, padded

  const int f = blockIdx.x;
  const int r8 = f & 7, rest = f >> 3;
  const int c6 = rest % 6, qt = rest / 6;
  const int pp = r8 + 8 * c6;          // 0..47
  const int b = pp / 12, hh = pp % 12;
  const int tid = threadIdx.x, lane = tid & 63, wq = tid >> 6;
  const int l15 = lane & 15, lg = lane >> 4;

  bf16x8 qreg0, qreg1;
  {
    const bf16* qsrc = Qp + (size_t)(b * 1024 + qt * 64 + wq * 16 + l15) * ldq + hh * 64 + lg * 8;
    qreg0 = *(const bf16x8*)qsrc;
    qreg1 = *(const bf16x8*)(qsrc + 32);
  }
  const char* Kbase = (const char*)(Kp + (size_t)b * 1024 * ldk + hh * 64);
  const char* Vbase = (const char*)(Vt + (size_t)(b * 12 + hh) * 64 * 1024);
  const bf16* biasRow = nullptr;
  if constexpr (CROSS)   // [b][q][h][k] layout
    biasRow = bias + ((size_t)(b * 1024 + qt * 64 + wq * 16 + l15) * 12 + hh) * 1024;

  f32x4 oacc[4];
  const f32x4 z = {0.f, 0.f, 0.f, 0.f};
  #pragma unroll
  for (int i = 0; i < 4; ++i) oacc[i] = z;
  float m_run = -1e30f, l_run = 0.f;

  char* PlW = (char*)&Pl[wq][0];
  const int swz = (l15 & 7) << 4;      // read-side XOR (row&7)<<4

  auto stage = [&](int buf, int t) {
    const int k0 = t * 64;
    #pragma unroll
    for (int jj = 0; jj < 2; ++jj) {
      const int c = jj * 256 + tid;                // 16B chunk id 0..511
      const int r = c >> 3;
      const int sw = ((c & 7) ^ (r & 7)) << 4;     // swizzled byte-col in row
      gload16(Kbase + ((size_t)(k0 + r) * ldk) * 2 + sw, (char*)&Kl[buf][0] + (size_t)c * 16);
      gload16(Vbase + (size_t)r * 2048 + (size_t)k0 * 2 + sw, (char*)&Vl[buf][0] + (size_t)c * 16);
    }
  };

  stage(0, 0);
  __syncthreads();   // prologue staging drained

  for (int t = 0; t < 16; ++t) {
    const int cur = t & 1;
    const int k0 = t * 64;
    if (t < 15) stage(cur ^ 1, t + 1);   // async prefetch; drained at loop-end barrier

    bf16x4 bv[4];
    if constexpr (CROSS) {
      const bf16* bp = biasRow + k0 + lg * 4;
      #pragma unroll
      for (int ni = 0; ni < 4; ++ni) bv[ni] = *(const bf16x4*)(bp + ni * 16);
    }

    // ---- S^T = K . Q^T ----
    f32x4 sacc[4];
    #pragma unroll
    for (int i = 0; i < 4; ++i) sacc[i] = z;
    #pragma unroll
    for (int ni = 0; ni < 4; ++ni) {
      const int rowb = (ni * 16 + l15) * 128;
      const bf16x8 a0 = *(const bf16x8*)((char*)&Kl[cur][0] + rowb + ((lg * 16) ^ swz));
      const bf16x8 a1 = *(const bf16x8*)((char*)&Kl[cur][0] + rowb + ((64 + lg * 16) ^ swz));
      sacc[ni] = mfma_bf16(a0, qreg0, sacc[ni]);
      sacc[ni] = mfma_bf16(a1, qreg1, sacc[ni]);
    }

    // ---- online softmax ----
    float sv[16];
    #pragma unroll
    for (int ni = 0; ni < 4; ++ni)
      #pragma unroll
      for (int r = 0; r < 4; ++r)
        sv[ni * 4 + r] = sacc[ni][r] * 0.125f;
    if constexpr (CROSS) {
      #pragma unroll
      for (int ni = 0; ni < 4; ++ni)
        #pragma unroll
        for (int r = 0; r < 4; ++r)
          sv[ni * 4 + r] += (float)bv[ni][r];
    }
    float mx = sv[0];
    #pragma unroll
    for (int jj = 1; jj < 16; ++jj) mx = fmaxf(mx, sv[jj]);
    mx = fmaxf(mx, __shfl_xor(mx, 16));
    mx = fmaxf(mx, __shfl_xor(mx, 32));
    const float mnew = fmaxf(m_run, mx);
    const float corr = __expf(m_run - mnew);
    m_run = mnew;
    float ps = 0.f;
    #pragma unroll
    for (int jj = 0; jj < 16; ++jj) { sv[jj] = __expf(sv[jj] - mnew); ps += sv[jj]; }
    l_run = l_run * corr + ps;

    // ---- P -> per-wave LDS (fragment-layout transpose) ----
    #pragma unroll
    for (int ni = 0; ni < 4; ++ni) {
      bf16x4 pw;
      #pragma unroll
      for (int r = 0; r < 4; ++r) pw[r] = (bf16)sv[ni * 4 + r];
      *(bf16x4*)(PlW + l15 * 144 + ni * 32 + lg * 8) = pw;
    }
    float cr[4];
    #pragma unroll
    for (int r = 0; r < 4; ++r) cr[r] = __shfl(corr, ((lane >> 4) << 2) + r);
    #pragma unroll
    for (int nd = 0; nd < 4; ++nd)
      #pragma unroll
      for (int r = 0; r < 4; ++r) oacc[nd][r] *= cr[r];

    // ---- O += P . V ----
    const bf16x8 p0 = *(const bf16x8*)(PlW + l15 * 144 + lg * 16);
    const bf16x8 p1 = *(const bf16x8*)(PlW + l15 * 144 + 64 + lg * 16);
    #pragma unroll
    for (int nd = 0; nd < 4; ++nd) {
      const int rowb = (nd * 16 + l15) * 128;
      const bf16x8 v0 = *(const bf16x8*)((char*)&Vl[cur][0] + rowb + ((lg * 16) ^ swz));
      const bf16x8 v1 = *(const bf16x8*)((char*)&Vl[cur][0] + rowb + ((64 + lg * 16) ^ swz));
      oacc[nd] = mfma_bf16(p0, v0, oacc[nd]);
      oacc[nd] = mfma_bf16(p1, v1, oacc[nd]);
    }
    __syncthreads();   // staging t+1 complete; all waves done with buf cur
  }

  // ---- finalize ----
  float ls = l_run + __shfl_xor(l_run, 16);
  ls += __shfl_xor(ls, 32);
  const float inv = 1.0f / ls;
  float ivr[4];
  #pragma unroll
  for (int r = 0; r < 4; ++r) ivr[r] = __shfl(inv, ((lane >> 4) << 2) + r);
  bf16* ob = Out + (size_t)(b * 1024 + qt * 64 + wq * 16 + lg * 4) * 768 + hh * 64 + l15;
  #pragma unroll
  for (int r = 0; r < 4; ++r)
    #pragma unroll
    for (int nd = 0; nd < 4; ++nd)
      ob[(size_t)r * 768 + nd * 16] = (bf16)(oacc[nd][r] * ivr[r]);
}

// ---------------- launcher ----------------
extern "C" void kernel_launch(void* const* d_in, const int* in_sizes, int n_in,
                              void* d_out, int out_size, void* d_ws, size_t ws_size,
                              hipStream_t stream)
{
  (void)in_sizes; (void)n_in; (void)out_size; (void)ws_size;
  const float* x    = (const float*)d_in[0];
  const float* y    = (const float*)d_in[1];
  const unsigned char* mask = (const unsigned char*)d_in[4];
  const float* sim  = (const float*)d_in[5];
  const float* ln1g = (const float*)d_in[6];
  const float* ln1b = (const float*)d_in[7];
  const float* ln2g = (const float*)d_in[8];
  const float* ln2b = (const float*)d_in[9];
  const float* ln3g = (const float*)d_in[10];
  const float* ln3b = (const float*)d_in[11];
  const float* lnyg = (const float*)d_in[12];
  const float* lnyb = (const float*)d_in[13];
  const float* qkvw = (const float*)d_in[14];
  const float* apw  = (const float*)d_in[15];
  const float* apb  = (const float*)d_in[16];
  const float* pqw  = (const float*)d_in[17];
  const float* pkw  = (const float*)d_in[18];
  const float* pvw  = (const float*)d_in[19];
  const float* cpw  = (const float*)d_in[20];
  const float* cpb  = (const float*)d_in[21];
  const float* f1w  = (const float*)d_in[22];
  const float* f1b  = (const float*)d_in[23];
  const float* f2w  = (const float*)d_in[24];
  const float* f2b  = (const float*)d_in[25];

  char* ws = (char*)d_ws;
  size_t off = 0;
  auto alloc = [&](size_t bytes) -> void* {
    off = (off + 255) & ~(size_t)255;
    void* p = ws + off;
    off += bytes;
    return p;
  };
  const size_t T = 4096;  // B*NQ
  bf16* w_qkv = (bf16*)alloc((size_t)2304 * 768 * 2);
  bf16* w_ap  = (bf16*)alloc((size_t)768 * 768 * 2);
  bf16* w_pq  = (bf16*)alloc((size_t)768 * 768 * 2);
  bf16* w_pkv = (bf16*)alloc((size_t)1536 * 768 * 2);
  bf16* w_cp  = (bf16*)alloc((size_t)768 * 768 * 2);
  bf16* w_f1  = (bf16*)alloc((size_t)3072 * 768 * 2);
  bf16* w_f2  = (bf16*)alloc((size_t)768 * 3072 * 2);
  bf16* xn    = (bf16*)alloc(T * 768 * 2);
  bf16* qkvo  = (bf16*)alloc(T * 2304 * 2);
  bf16* vt    = (bf16*)alloc((size_t)48 * 64 * 1024 * 2);
  bf16* sa    = (bf16*)alloc(T * 768 * 2);
  float* x1   = (float*)alloc(T * 768 * 4);
  bf16* yln   = (bf16*)alloc(T * 768 * 2);
  bf16* xn2   = (bf16*)alloc(T * 768 * 2);
  bf16* cqf   = (bf16*)alloc(T * 768 * 2);
  bf16* ckv   = (bf16*)alloc(T * 1536 * 2);
  bf16* cvtT  = (bf16*)alloc((size_t)48 * 64 * 1024 * 2);
  bf16* biasA = (bf16*)alloc((size_t)4 * 1024 * 12 * 1024 * 2);  // [b][q][h][k]
  bf16* ca    = (bf16*)alloc(T * 768 * 2);
  float* x2   = (float*)alloc(T * 768 * 4);
  bf16* xn3   = (bf16*)alloc(T * 768 * 2);
  bf16* hbuf  = (bf16*)alloc(T * 3072 * 2);

  CvtArgs a;
  {
    const float* srcs[8] = {qkvw, apw, pqw, pkw, pvw, cpw, f1w, f2w};
    bf16* dsts[8] = {w_qkv, w_ap, w_pq, w_pkv, w_pkv + 768 * 768, w_cp, w_f1, w_f2};
    const int n4s[8] = {442368, 147456, 147456, 147456, 147456, 147456, 589824, 589824};
    int cum = 0;
    for (int j = 0; j < 8; ++j) {
      a.src[j] = srcs[j]; a.dst[j] = dsts[j];
      cum += n4s[j]; a.end[j] = cum;
    }
  }

  // D1: cvt + ln(x) + ln(y)
  prep_k<<<4352, 256, 0, stream>>>(a, x, ln1g, ln1b, xn, y, lnyg, lnyb, yln);

  // D2: bias precompute (linearized IO, standalone for measurement)
  bias_k<<<4096, 256, 0, stream>>>(sim, mask, biasA);

  // D3: qkv GEMM (+ fused V transpose)
  gemm_bt<128,128,false,false,false,true,true><<<576, 256, 0, stream>>>(
      xn, w_qkv, nullptr, nullptr, qkvo, nullptr, vt, 1536, 4, 2304, 768);

  // D4: self-attention
  fattn_k<0><<<768, 256, 0, stream>>>(
      qkvo, 2304, qkvo + 768, 2304, vt, nullptr, sa);

  // D5: aproj + pkv (both compute-bound GEMMs)
  apkv_k<<<768, 256, 0, stream>>>(sa, w_ap, apb, x, x1, yln, w_pkv, ckv, cvtT);

  // D6: ln2
  ln_k<<<1024, 256, 0, stream>>>(x1, ln2g, ln2b, xn2);

  // D7: pq
  gemm_bt<64,128,false,false,false,true,false><<<384, 256, 0, stream>>>(
      xn2, w_pq, nullptr, nullptr, cqf, nullptr, nullptr, 0, 8, 768, 768);

  // D8: cross-attention
  fattn_k<1><<<768, 256, 0, stream>>>(
      cqf, 768, ckv, 1536, cvtT, biasA, ca);

  // D9: cproj
  gemm_bt<64,128,true,false,true,false,false><<<384, 256, 0, stream>>>(
      ca, w_cp, cpb, x1, nullptr, x2, nullptr, 0, 8, 768, 768);

  // D10: ln3
  ln_k<<<1024, 256, 0, stream>>>(x2, ln3g, ln3b, xn3);

  // D11: fc1
  gemm_bt<128,128,true,true,false,true,false><<<768, 256, 0, stream>>>(
      xn3, w_f1, f1b, nullptr, hbuf, nullptr, nullptr, 0, 4, 3072, 768);

  // D12: fc2 + y passthrough copy
  fc2copy_k<<<896, 256, 0, stream>>>(
      hbuf, w_f2, f2b, x2, (float*)d_out, y, (float*)d_out + 3145728);
}

// Round 13
// 349.890 us; speedup vs baseline: 1.1088x; 1.1088x over previous
//
#include <hip/hip_runtime.h>
#include <cstdint>
#include <cstddef>

// DinoDecoderBlock on MI355X (gfx950).
// B=4 NQ=NK=1024 C=768 H=12 DH=64, scale=1/8, eps=1e-5.
// R13: bias precompute spread as tail blocks across the 4 compute dispatches
//      before cross-attn (qkv, fattn0, apkv, pq) -> HBM streaming hides under
//      MFMA. Register bias body (no LDS), wave-shfl mask detect.
//      (R10-R12: standalone bias pinned at ~100us/2-3TB/s across 3 structures.)

typedef __bf16 bf16;
typedef __attribute__((ext_vector_type(8))) __bf16 bf16x8;
typedef __attribute__((ext_vector_type(4))) __bf16 bf16x4;
typedef __attribute__((ext_vector_type(4))) float f32x4;

typedef __attribute__((address_space(1))) void gvoid;
typedef __attribute__((address_space(3))) void lvoid;

#define DEVI static __device__ __forceinline__

DEVI void gload16(const void* g, void* l) {
  __builtin_amdgcn_global_load_lds((gvoid*)(uintptr_t)g, (lvoid*)(uintptr_t)l, 16, 0, 0);
}

DEVI f32x4 mfma_bf16(bf16x8 a, bf16x8 b, f32x4 c) {
  return __builtin_amdgcn_mfma_f32_16x16x32_bf16(a, b, c, 0, 0, 0);
}

// ================= device bodies =================

// ---- GEMM tile body ----
template<int BM, int BN, bool BIAS, bool GELU, bool RES, bool OBF, bool VT>
DEVI void gemm_dev(bf16* As, bf16* Bs, int by, int bx,
                   const bf16* __restrict__ A, const bf16* __restrict__ Bt,
                   const float* __restrict__ bias, const float* __restrict__ res,
                   bf16* __restrict__ Cb, float* __restrict__ Cf,
                   bf16* __restrict__ vtOut, int vtBase, int N, int K)
{
  constexpr int WM = BM / 2, WN = BN / 2;
  constexpr int FM = WM / 16, FN = WN / 16;
  const int tid = threadIdx.x;
  const int lane = tid & 63;
  const int wv = tid >> 6;
  const int wr = wv >> 1, wc = wv & 1;
  const int l15 = lane & 15, lg = lane >> 4;
  const int bm = by * BM, bn = bx * BN;

  f32x4 acc[FM][FN];
  const f32x4 z = {0.f, 0.f, 0.f, 0.f};
  #pragma unroll
  for (int i = 0; i < FM; ++i)
    #pragma unroll
    for (int jj = 0; jj < FN; ++jj) acc[i][jj] = z;

  for (int k0 = 0; k0 < K; k0 += 64) {
    __syncthreads();
    #pragma unroll
    for (int c = tid; c < BM * 8; c += 256) {
      const int row = c >> 3, colb = (c & 7) << 4;
      gload16((const char*)A + ((size_t)(bm + row) * K + k0) * 2 + colb,
              (char*)As + (size_t)c * 16);
    }
    #pragma unroll
    for (int c = tid; c < BN * 8; c += 256) {
      const int row = c >> 3, colb = (c & 7) << 4;
      gload16((const char*)Bt + ((size_t)(bn + row) * K + k0) * 2 + colb,
              (char*)Bs + (size_t)c * 16);
    }
    __syncthreads();
    #pragma unroll
    for (int kk = 0; kk < 64; kk += 32) {
      bf16x8 af[FM], bfr[FN];
      #pragma unroll
      for (int mi = 0; mi < FM; ++mi)
        af[mi] = *(const bf16x8*)(As + (size_t)(wr * WM + mi * 16 + l15) * 64 + kk + lg * 8);
      #pragma unroll
      for (int ni = 0; ni < FN; ++ni)
        bfr[ni] = *(const bf16x8*)(Bs + (size_t)(wc * WN + ni * 16 + l15) * 64 + kk + lg * 8);
      #pragma unroll
      for (int mi = 0; mi < FM; ++mi)
        #pragma unroll
        for (int ni = 0; ni < FN; ++ni)
          acc[mi][ni] = mfma_bf16(af[mi], bfr[ni], acc[mi][ni]);
    }
  }

  #pragma unroll
  for (int mi = 0; mi < FM; ++mi) {
    const int row0 = bm + wr * WM + mi * 16 + lg * 4;
    #pragma unroll
    for (int ni = 0; ni < FN; ++ni) {
      const int col = bn + wc * WN + ni * 16 + l15;
      if constexpr (VT) {
        if (col >= vtBase) {   // V channel: store transposed, 4 consecutive n
          const int hd = col - vtBase;            // h*64+d
          const int bb = row0 >> 10, n0 = row0 & 1023;
          bf16x4 ov;
          #pragma unroll
          for (int r = 0; r < 4; ++r) ov[r] = (bf16)acc[mi][ni][r];
          *(bf16x4*)(vtOut + ((size_t)(bb * 768 + hd)) * 1024 + n0) = ov;
          continue;
        }
      }
      #pragma unroll
      for (int r = 0; r < 4; ++r) {
        float v = acc[mi][ni][r];
        if constexpr (BIAS) v += bias[col];
        if constexpr (GELU) v = 0.5f * v * (1.0f + erff(v * 0.70710678118654752f));
        if constexpr (RES)  v += res[(size_t)(row0 + r) * N + col];
        if constexpr (OBF)  Cb[(size_t)(row0 + r) * N + col] = (bf16)v;
        else                Cf[(size_t)(row0 + r) * N + col] = v;
      }
    }
  }
}

// ---- register bias body: one (b,q) per block, no LDS, no block barrier ----
// out[b][q][h][k] = sim[b,h,q,k] - mean_h + (mask[q,k]?0:-1e30)
DEVI void biasr_dev(int blk,
                    const float* __restrict__ sim,
                    const unsigned char* __restrict__ mask,
                    bf16* __restrict__ out)
{
  const int b = blk >> 10, q = blk & 1023;
  const int t = threadIdx.x, lane = t & 63;

  // mask dtype detect per wave (1KB window): int32 0/1 has zero non-LSB bytes
  int ds = 0;
  #pragma unroll
  for (int i = 0; i < 4; ++i) {
    const int idx = (lane * 4 + i) * 4;
    ds += mask[idx + 1] + mask[idx + 2] + mask[idx + 3];
  }
  #pragma unroll
  for (int o = 32; o; o >>= 1) ds += __shfl_xor(ds, o);
  const int msh = (ds == 0) ? 2 : 0;

  const int k4 = t * 4;
  const float* sb = sim + (size_t)b * 12 * 1048576;
  f32x4 sv[12];
  f32x4 acc = {0.f, 0.f, 0.f, 0.f};
  #pragma unroll
  for (int h = 0; h < 12; ++h) {
    sv[h] = *(const f32x4*)(sb + ((size_t)h * 1024 + q) * 1024 + k4);
    acc += sv[h];
  }
  const f32x4 mean = acc * (1.0f / 12.0f);

  float mb[4];
  if (msh == 0) {
    const uchar4 mv = *(const uchar4*)(mask + (size_t)q * 1024 + k4);
    mb[0] = mv.x ? 0.f : -1e30f; mb[1] = mv.y ? 0.f : -1e30f;
    mb[2] = mv.z ? 0.f : -1e30f; mb[3] = mv.w ? 0.f : -1e30f;
  } else {
    const int4 mv = *(const int4*)((const int*)mask + (size_t)q * 1024 + k4);
    mb[0] = mv.x ? 0.f : -1e30f; mb[1] = mv.y ? 0.f : -1e30f;
    mb[2] = mv.z ? 0.f : -1e30f; mb[3] = mv.w ? 0.f : -1e30f;
  }

  bf16* ob = out + (size_t)(b * 1024 + q) * 12 * 1024;
  #pragma unroll
  for (int h = 0; h < 12; ++h) {
    bf16x4 o;
    #pragma unroll
    for (int j = 0; j < 4; ++j)
      o[j] = (bf16)(sv[h][j] - mean[j] + mb[j]);
    *(bf16x4*)(ob + h * 1024 + k4) = o;
  }
}

// ---- wave-parallel LayerNorm: one wave = one row of 768, no barriers ----
DEVI void lnw_dev(int row,
                  const float* __restrict__ xin, const float* __restrict__ g,
                  const float* __restrict__ be, bf16* __restrict__ out)
{
  const int lane = threadIdx.x & 63;
  const f32x4* xr = (const f32x4*)(xin + (size_t)row * 768);
  f32x4 v[3];
  #pragma unroll
  for (int j = 0; j < 3; ++j) v[j] = xr[lane + 64 * j];
  float s = 0.f;
  #pragma unroll
  for (int j = 0; j < 3; ++j) s += v[j][0] + v[j][1] + v[j][2] + v[j][3];
  #pragma unroll
  for (int o = 32; o; o >>= 1) s += __shfl_xor(s, o);
  const float mean = s * (1.0f / 768.0f);
  float q = 0.f;
  #pragma unroll
  for (int j = 0; j < 3; ++j)
    #pragma unroll
    for (int e = 0; e < 4; ++e) { const float d = v[j][e] - mean; q += d * d; }
  #pragma unroll
  for (int o = 32; o; o >>= 1) q += __shfl_xor(q, o);
  const float inv = rsqrtf(q * (1.0f / 768.0f) + 1e-5f);
  #pragma unroll
  for (int j = 0; j < 3; ++j) {
    const int c = lane + 64 * j;
    const f32x4 gv = ((const f32x4*)g)[c];
    const f32x4 bv = ((const f32x4*)be)[c];
    bf16x4 o4;
    #pragma unroll
    for (int e = 0; e < 4; ++e)
      o4[e] = (bf16)((v[j][e] - mean) * inv * gv[e] + bv[e]);
    *((bf16x4*)out + (size_t)row * 192 + c) = o4;
  }
}

// ================= kernels =================

struct CvtArgs {
  const float* src[8];
  bf16* dst[8];
  int end[8];
};

// D1 (streaming): cvt [0,2304) 4 chunks/thread + LN [2304,4352) wave-parallel
__global__ __launch_bounds__(256)
void prep_k(CvtArgs a,
            const float* __restrict__ x, const float* __restrict__ g1,
            const float* __restrict__ b1, bf16* __restrict__ xn,
            const float* __restrict__ y, const float* __restrict__ gy,
            const float* __restrict__ by_, bf16* __restrict__ yln)
{
  const int f = blockIdx.x;
  const int t = threadIdx.x;
  if (f < 2304) {
    #pragma unroll
    for (int j = 0; j < 4; ++j) {
      const int i = f * 1024 + j * 256 + t;
      int s = 0;
      #pragma unroll
      for (int k = 0; k < 7; ++k) s += (i >= a.end[k]) ? 1 : 0;
      const int base = s ? a.end[s - 1] : 0;
      const int off = i - base;
      const f32x4 v = *((const f32x4*)a.src[s] + off);
      bf16x4 o;
      o[0] = (bf16)v[0]; o[1] = (bf16)v[1]; o[2] = (bf16)v[2]; o[3] = (bf16)v[3];
      *(bf16x4*)(a.dst[s] + (size_t)off * 4) = o;
    }
  } else {
    const int row = (f - 2304) * 4 + (t >> 6);
    if (row < 4096) lnw_dev(row, x, g1, b1, xn);
    else            lnw_dev(row - 4096, y, gy, by_, yln);
  }
}

// GEMM wrapper with optional bias tail blocks
template<int BM, int BN, bool BIAS, bool GELU, bool RES, bool OBF, bool VT>
__global__ __launch_bounds__(256)
void gemm_bt(const bf16* __restrict__ A, const bf16* __restrict__ Bt,
             const float* __restrict__ bias, const float* __restrict__ res,
             bf16* __restrict__ Cb, float* __restrict__ Cf,
             bf16* __restrict__ vtOut, int vtBase,
             int nyPerXcd, int N, int K,
             int nCompute,
             const float* __restrict__ bsim, const unsigned char* __restrict__ bmask,
             bf16* __restrict__ bout, int bbase)
{
  __shared__ bf16 As[BM * 64];
  __shared__ bf16 Bs[BN * 64];
  const int f = blockIdx.x;
  if (f >= nCompute) {           // bias tail
    biasr_dev(bbase + f - nCompute, bsim, bmask, bout);
    return;
  }
  const int xcd = f & 7, j = f >> 3;
  const int by = xcd + 8 * (j % nyPerXcd);
  const int bx = j / nyPerXcd;
  gemm_dev<BM,BN,BIAS,GELU,RES,OBF,VT>(As, Bs, by, bx,
      A, Bt, bias, res, Cb, Cf, vtOut, vtBase, N, K);
}

// aproj (0..383) + pkv (384..767) + bias tail (768..)
__global__ __launch_bounds__(256)
void apkv_k(const bf16* __restrict__ sa, const bf16* __restrict__ w_ap,
            const float* __restrict__ apb, const float* __restrict__ x,
            float* __restrict__ x1,
            const bf16* __restrict__ yln, const bf16* __restrict__ w_pkv,
            bf16* __restrict__ ckv, bf16* __restrict__ cvtT,
            const float* __restrict__ bsim, const unsigned char* __restrict__ bmask,
            bf16* __restrict__ bout, int bbase)
{
  __shared__ bf16 As[128 * 64];
  __shared__ bf16 Bs[128 * 64];
  const int f = blockIdx.x;
  if (f >= 768) {
    biasr_dev(bbase + f - 768, bsim, bmask, bout);
    return;
  }
  if (f < 384) {
    const int xcd = f & 7, j = f >> 3;
    const int by = xcd + 8 * (j % 8);
    const int bx = j / 8;
    gemm_dev<64,128,true,false,true,false,false>(As, Bs, by, bx,
        sa, w_ap, apb, x, nullptr, x1, nullptr, 0, 768, 768);
  } else {
    const int g = f - 384;
    const int xcd = g & 7, j = g >> 3;
    const int by = xcd + 8 * (j % 4);
    const int bx = j / 4;
    gemm_dev<128,128,false,false,false,true,true>(As, Bs, by, bx,
        yln, w_pkv, nullptr, nullptr, ckv, nullptr, cvtT, 768, 1536, 768);
  }
}

// fc2 (0..383) + y-copy (384..895, grid-stride)
__global__ __launch_bounds__(256)
void fc2copy_k(const bf16* __restrict__ hbuf, const bf16* __restrict__ w_f2,
               const float* __restrict__ f2b, const float* __restrict__ x2,
               float* __restrict__ outp,
               const float* __restrict__ y, float* __restrict__ ycopy)
{
  __shared__ bf16 As[128 * 64];
  __shared__ bf16 Bs[128 * 64];
  const int f = blockIdx.x;
  if (f < 384) {
    const int xcd = f & 7, j = f >> 3;
    const int by = xcd + 8 * (j % 8);
    const int bx = j / 8;
    gemm_dev<64,128,true,false,true,false,false>(As, Bs, by, bx,
        hbuf, w_f2, f2b, x2, nullptr, outp, nullptr, 0, 768, 3072);
  } else {
    for (int i = (f - 384) * 256 + threadIdx.x; i < 786432; i += 512 * 256)
      ((f32x4*)ycopy)[i] = ((const f32x4*)y)[i];
  }
}

// standalone LayerNorm (ln2 / ln3): 4 rows/block, wave-parallel
__global__ __launch_bounds__(256)
void ln_k(const float* __restrict__ xin, const float* __restrict__ g,
          const float* __restrict__ be, bf16* __restrict__ out)
{
  lnw_dev(blockIdx.x * 4 + (threadIdx.x >> 6), xin, g, be, out);
}

// ---------------- flash attention: 64 q-rows/block, 4 waves, online softmax ----
// CROSS: bias layout [b][q][h][k] (bf16). Optional bias tail blocks (>= nCompute).
template<int CROSS>
__global__ __launch_bounds__(256, 3)
void fattn_k(const bf16* __restrict__ Qp, int ldq,
             const bf16* __restrict__ Kp, int ldk,
             const bf16* __restrict__ Vt,
             const bf16* __restrict__ bias,
             bf16* __restrict__ Out,
             int nCompute,
             const float* __restrict__ bsim, const unsigned char* __restrict__ bmask,
             bf16* __restrict__ bout, int bbase)
{
  __shared__ bf16 Kl[2][64 * 64];     // 16 KB, [krow][c] swizzled
  __shared__ bf16 Vl[2][64 * 64];     // 16 KB, [d][k]   swizzled
  __shared__ bf16 Pl[4][16 * 72];     // per-wave P tile, padded

  const int f = blockIdx.x;
  if (f >= nCompute) {
    biasr_dev(bbase + f - nCompute, bsim, bmask, bout);
    return;
  }
  const int r8 = f & 7, rest = f >> 3;
  const int c6 = rest % 6, qt = rest / 6;
  const int pp = r8 + 8 * c6;          // 0..47
  const int b = pp / 12, hh = pp % 12;
  const int tid = threadIdx.x, lane = tid & 63, wq = tid >> 6;
  const int l15 = lane & 15, lg = lane >> 4;

  bf16x8 qreg0, qreg1;
  {
    const bf16* qsrc = Qp + (size_t)(b * 1024 + qt * 64 + wq * 16 + l15) * ldq + hh * 64 + lg * 8;
    qreg0 = *(const bf16x8*)qsrc;
    qreg1 = *(const bf16x8*)(qsrc + 32);
  }
  const char* Kbase = (const char*)(Kp + (size_t)b * 1024 * ldk + hh * 64);
  const char* Vbase = (const char*)(Vt + (size_t)(b * 12 + hh) * 64 * 1024);
  const bf16* biasRow = nullptr;
  if constexpr (CROSS)   // [b][q][h][k] layout
    biasRow = bias + ((size_t)(b * 1024 + qt * 64 + wq * 16 + l15) * 12 + hh) * 1024;

  f32x4 oacc[4];
  const f32x4 z = {0.f, 0.f, 0.f, 0.f};
  #pragma unroll
  for (int i = 0; i < 4; ++i) oacc[i] = z;
  float m_run = -1e30f, l_run = 0.f;

  char* PlW = (char*)&Pl[wq][0];
  const int swz = (l15 & 7) << 4;      // read-side XOR (row&7)<<4

  auto stage = [&](int buf, int t) {
    const int k0 = t * 64;
    #pragma unroll
    for (int jj = 0; jj < 2; ++jj) {
      const int c = jj * 256 + tid;                // 16B chunk id 0..511
      const int r = c >> 3;
      const int sw = ((c & 7) ^ (r & 7)) << 4;     // swizzled byte-col in row
      gload16(Kbase + ((size_t)(k0 + r) * ldk) * 2 + sw, (char*)&Kl[buf][0] + (size_t)c * 16);
      gload16(Vbase + (size_t)r * 2048 + (size_t)k0 * 2 + sw, (char*)&Vl[buf][0] + (size_t)c * 16);
    }
  };

  stage(0, 0);
  __syncthreads();   // prologue staging drained

  for (int t = 0; t < 16; ++t) {
    const int cur = t & 1;
    const int k0 = t * 64;
    if (t < 15) stage(cur ^ 1, t + 1);   // async prefetch; drained at loop-end barrier

    bf16x4 bv[4];
    if constexpr (CROSS) {
      const bf16* bp = biasRow + k0 + lg * 4;
      #pragma unroll
      for (int ni = 0; ni < 4; ++ni) bv[ni] = *(const bf16x4*)(bp + ni * 16);
    }

    // ---- S^T = K . Q^T ----
    f32x4 sacc[4];
    #pragma unroll
    for (int i = 0; i < 4; ++i) sacc[i] = z;
    #pragma unroll
    for (int ni = 0; ni < 4; ++ni) {
      const int rowb = (ni * 16 + l15) * 128;
      const bf16x8 a0 = *(const bf16x8*)((char*)&Kl[cur][0] + rowb + ((lg * 16) ^ swz));
      const bf16x8 a1 = *(const bf16x8*)((char*)&Kl[cur][0] + rowb + ((64 + lg * 16) ^ swz));
      sacc[ni] = mfma_bf16(a0, qreg0, sacc[ni]);
      sacc[ni] = mfma_bf16(a1, qreg1, sacc[ni]);
    }

    // ---- online softmax ----
    float sv[16];
    #pragma unroll
    for (int ni = 0; ni < 4; ++ni)
      #pragma unroll
      for (int r = 0; r < 4; ++r)
        sv[ni * 4 + r] = sacc[ni][r] * 0.125f;
    if constexpr (CROSS) {
      #pragma unroll
      for (int ni = 0; ni < 4; ++ni)
        #pragma unroll
        for (int r = 0; r < 4; ++r)
          sv[ni * 4 + r] += (float)bv[ni][r];
    }
    float mx = sv[0];
    #pragma unroll
    for (int jj = 1; jj < 16; ++jj) mx = fmaxf(mx, sv[jj]);
    mx = fmaxf(mx, __shfl_xor(mx, 16));
    mx = fmaxf(mx, __shfl_xor(mx, 32));
    const float mnew = fmaxf(m_run, mx);
    const float corr = __expf(m_run - mnew);
    m_run = mnew;
    float ps = 0.f;
    #pragma unroll
    for (int jj = 0; jj < 16; ++jj) { sv[jj] = __expf(sv[jj] - mnew); ps += sv[jj]; }
    l_run = l_run * corr + ps;

    // ---- P -> per-wave LDS (fragment-layout transpose) ----
    #pragma unroll
    for (int ni = 0; ni < 4; ++ni) {
      bf16x4 pw;
      #pragma unroll
      for (int r = 0; r < 4; ++r) pw[r] = (bf16)sv[ni * 4 + r];
      *(bf16x4*)(PlW + l15 * 144 + ni * 32 + lg * 8) = pw;
    }
    float cr[4];
    #pragma unroll
    for (int r = 0; r < 4; ++r) cr[r] = __shfl(corr, ((lane >> 4) << 2) + r);
    #pragma unroll
    for (int nd = 0; nd < 4; ++nd)
      #pragma unroll
      for (int r = 0; r < 4; ++r) oacc[nd][r] *= cr[r];

    // ---- O += P . V ----
    const bf16x8 p0 = *(const bf16x8*)(PlW + l15 * 144 + lg * 16);
    const bf16x8 p1 = *(const bf16x8*)(PlW + l15 * 144 + 64 + lg * 16);
    #pragma unroll
    for (int nd = 0; nd < 4; ++nd) {
      const int rowb = (nd * 16 + l15) * 128;
      const bf16x8 v0 = *(const bf16x8*)((char*)&Vl[cur][0] + rowb + ((lg * 16) ^ swz));
      const bf16x8 v1 = *(const bf16x8*)((char*)&Vl[cur][0] + rowb + ((64 + lg * 16) ^ swz));
      oacc[nd] = mfma_bf16(p0, v0, oacc[nd]);
      oacc[nd] = mfma_bf16(p1, v1, oacc[nd]);
    }
    __syncthreads();   // staging t+1 complete; all waves done with buf cur
  }

  // ---- finalize ----
  float ls = l_run + __shfl_xor(l_run, 16);
  ls += __shfl_xor(ls, 32);
  const float inv = 1.0f / ls;
  float ivr[4];
  #pragma unroll
  for (int r = 0; r < 4; ++r) ivr[r] = __shfl(inv, ((lane >> 4) << 2) + r);
  bf16* ob = Out + (size_t)(b * 1024 + qt * 64 + wq * 16 + lg * 4) * 768 + hh * 64 + l15;
  #pragma unroll
  for (int r = 0; r < 4; ++r)
    #pragma unroll
    for (int nd = 0; nd < 4; ++nd)
      ob[(size_t)r * 768 + nd * 16] = (bf16)(oacc[nd][r] * ivr[r]);
}

// ---------------- launcher ----------------
extern "C" void kernel_launch(void* const* d_in, const int* in_sizes, int n_in,
                              void* d_out, int out_size, void* d_ws, size_t ws_size,
                              hipStream_t stream)
{
  (void)in_sizes; (void)n_in; (void)out_size; (void)ws_size;
  const float* x    = (const float*)d_in[0];
  const float* y    = (const float*)d_in[1];
  const unsigned char* mask = (const unsigned char*)d_in[4];
  const float* sim  = (const float*)d_in[5];
  const float* ln1g = (const float*)d_in[6];
  const float* ln1b = (const float*)d_in[7];
  const float* ln2g = (const float*)d_in[8];
  const float* ln2b = (const float*)d_in[9];
  const float* ln3g = (const float*)d_in[10];
  const float* ln3b = (const float*)d_in[11];
  const float* lnyg = (const float*)d_in[12];
  const float* lnyb = (const float*)d_in[13];
  const float* qkvw = (const float*)d_in[14];
  const float* apw  = (const float*)d_in[15];
  const float* apb  = (const float*)d_in[16];
  const float* pqw  = (const float*)d_in[17];
  const float* pkw  = (const float*)d_in[18];
  const float* pvw  = (const float*)d_in[19];
  const float* cpw  = (const float*)d_in[20];
  const float* cpb  = (const float*)d_in[21];
  const float* f1w  = (const float*)d_in[22];
  const float* f1b  = (const float*)d_in[23];
  const float* f2w  = (const float*)d_in[24];
  const float* f2b  = (const float*)d_in[25];

  char* ws = (char*)d_ws;
  size_t off = 0;
  auto alloc = [&](size_t bytes) -> void* {
    off = (off + 255) & ~(size_t)255;
    void* p = ws + off;
    off += bytes;
    return p;
  };
  const size_t T = 4096;  // B*NQ
  bf16* w_qkv = (bf16*)alloc((size_t)2304 * 768 * 2);
  bf16* w_ap  = (bf16*)alloc((size_t)768 * 768 * 2);
  bf16* w_pq  = (bf16*)alloc((size_t)768 * 768 * 2);
  bf16* w_pkv = (bf16*)alloc((size_t)1536 * 768 * 2);
  bf16* w_cp  = (bf16*)alloc((size_t)768 * 768 * 2);
  bf16* w_f1  = (bf16*)alloc((size_t)3072 * 768 * 2);
  bf16* w_f2  = (bf16*)alloc((size_t)768 * 3072 * 2);
  bf16* xn    = (bf16*)alloc(T * 768 * 2);
  bf16* qkvo  = (bf16*)alloc(T * 2304 * 2);
  bf16* vt    = (bf16*)alloc((size_t)48 * 64 * 1024 * 2);
  bf16* sa    = (bf16*)alloc(T * 768 * 2);
  float* x1   = (float*)alloc(T * 768 * 4);
  bf16* yln   = (bf16*)alloc(T * 768 * 2);
  bf16* xn2   = (bf16*)alloc(T * 768 * 2);
  bf16* cqf   = (bf16*)alloc(T * 768 * 2);
  bf16* ckv   = (bf16*)alloc(T * 1536 * 2);
  bf16* cvtT  = (bf16*)alloc((size_t)48 * 64 * 1024 * 2);
  bf16* biasA = (bf16*)alloc((size_t)4 * 1024 * 12 * 1024 * 2);  // [b][q][h][k]
  bf16* ca    = (bf16*)alloc(T * 768 * 2);
  float* x2   = (float*)alloc(T * 768 * 4);
  bf16* xn3   = (bf16*)alloc(T * 768 * 2);
  bf16* hbuf  = (bf16*)alloc(T * 3072 * 2);

  CvtArgs a;
  {
    const float* srcs[8] = {qkvw, apw, pqw, pkw, pvw, cpw, f1w, f2w};
    bf16* dsts[8] = {w_qkv, w_ap, w_pq, w_pkv, w_pkv + 768 * 768, w_cp, w_f1, w_f2};
    const int n4s[8] = {442368, 147456, 147456, 147456, 147456, 147456, 589824, 589824};
    int cum = 0;
    for (int j = 0; j < 8; ++j) {
      a.src[j] = srcs[j]; a.dst[j] = dsts[j];
      cum += n4s[j]; a.end[j] = cum;
    }
  }

  // D1: cvt + ln(x) + ln(y)
  prep_k<<<4352, 256, 0, stream>>>(a, x, ln1g, ln1b, xn, y, lnyg, lnyb, yln);

  // D2: qkv GEMM (+V transpose) + bias chunk 0 (blocks 576..1599)
  gemm_bt<128,128,false,false,false,true,true><<<1600, 256, 0, stream>>>(
      xn, w_qkv, nullptr, nullptr, qkvo, nullptr, vt, 1536, 4, 2304, 768,
      576, sim, mask, biasA, 0);

  // D3: self-attention + bias chunk 1 (blocks 768..1791)
  fattn_k<0><<<1792, 256, 0, stream>>>(
      qkvo, 2304, qkvo + 768, 2304, vt, nullptr, sa,
      768, sim, mask, biasA, 1024);

  // D4: aproj + pkv + bias chunk 2 (blocks 768..1791)
  apkv_k<<<1792, 256, 0, stream>>>(sa, w_ap, apb, x, x1, yln, w_pkv, ckv, cvtT,
                                   sim, mask, biasA, 2048);

  // D5: ln2
  ln_k<<<1024, 256, 0, stream>>>(x1, ln2g, ln2b, xn2);

  // D6: pq + bias chunk 3 (blocks 384..1407)
  gemm_bt<64,128,false,false,false,true,false><<<1408, 256, 0, stream>>>(
      xn2, w_pq, nullptr, nullptr, cqf, nullptr, nullptr, 0, 8, 768, 768,
      384, sim, mask, biasA, 3072);

  // D7: cross-attention (no tail)
  fattn_k<1><<<768, 256, 0, stream>>>(
      cqf, 768, ckv, 1536, cvtT, biasA, ca,
      768, sim, mask, biasA, 0);

  // D8: cproj (no tail)
  gemm_bt<64,128,true,false,true,false,false><<<384, 256, 0, stream>>>(
      ca, w_cp, cpb, x1, nullptr, x2, nullptr, 0, 8, 768, 768,
      384, sim, mask, biasA, 0);

  // D9: ln3
  ln_k<<<1024, 256, 0, stream>>>(x2, ln3g, ln3b, xn3);

  // D10: fc1 (no tail)
  gemm_bt<128,128,true,true,false,true,false><<<768, 256, 0, stream>>>(
      xn3, w_f1, f1b, nullptr, hbuf, nullptr, nullptr, 0, 4, 3072, 768,
      768, sim, mask, biasA, 0);

  // D11: fc2 + y passthrough copy
  fc2copy_k<<<896, 256, 0, stream>>>(
      hbuf, w_f2, f2b, x2, (float*)d_out, y, (float*)d_out + 3145728);
}